// Round 5
// baseline (225.521 us; speedup 1.0000x reference)
//
#include <hip/hip_runtime.h>

#define B_ 2048
#define T_ 256
#define NV_ 32
#define H_ 64
#define L_ 32
#define OH_ 64
#define NSTEP 16
#define DEPTH 6

typedef _Float16 f16x8 __attribute__((ext_vector_type(8)));
typedef _Float16 f16x4 __attribute__((ext_vector_type(4)));
typedef float f32x4 __attribute__((ext_vector_type(4)));

#define MFMA16(a, b, c) __builtin_amdgcn_mfma_f32_16x16x32_f16((a), (b), (c), 0, 0, 0)

__device__ __forceinline__ float rcp_(float x) { return __builtin_amdgcn_rcpf(x); }
__device__ __forceinline__ float sigm(float x) { return rcp_(1.0f + __expf(-x)); }
__device__ __forceinline__ float tanh_(float x) { return 2.0f * rcp_(1.0f + __expf(-2.0f * x)) - 1.0f; }

__device__ __forceinline__ f16x8 pack8(f32x4 a, f32x4 b) {
    f16x8 r;
    r[0] = (_Float16)a[0]; r[1] = (_Float16)a[1]; r[2] = (_Float16)a[2]; r[3] = (_Float16)a[3];
    r[4] = (_Float16)b[0]; r[5] = (_Float16)b[1]; r[6] = (_Float16)b[2]; r[7] = (_Float16)b[3];
    return r;
}

// ---------------------------------------------------------------------------
// GRU encoder: 128 blocks x 4 waves, swapped orientation (gates^T = W * x^T),
// wave w owns gate features 16w..16w+15 of r,z,n. SPIN-FLAG sync replaces
// s_barrier: each wave, after its h-write, does lgkmcnt(0) -> ds_add(cnt) ->
// polls until cnt >= 4*(t+1). A wave's increment proves its step-t reads AND
// writes are complete, so a fast wave entering t+1 cannot overwrite a buffer
// a slow wave still reads (same guarantee as s_barrier, without the
// low-occupancy barrier sleep/wake cost). Depth-6 register prefetch of x
// (named sets, static indexing) keeps ~6 steps of slack over the measured
// ~3000-cy global load latency.
// ---------------------------------------------------------------------------
__global__ __launch_bounds__(256) void gru_kernel(
    const float* __restrict__ values, const float* __restrict__ mask,
    const int* __restrict__ seql, const float* __restrict__ eps,
    const float* __restrict__ W_ih, const float* __restrict__ W_hh,
    const float* __restrict__ b_ih, const float* __restrict__ b_hh,
    const float* __restrict__ W_z0, const float* __restrict__ b_z0,
    float* __restrict__ z0ws, float* __restrict__ parts)
{
    const int tid = threadIdx.x;
    const int w   = tid >> 6;
    const int l   = tid & 63;
    const int c   = l & 15;
    const int g4  = l >> 4;
    const int b0  = blockIdx.x * 16;

    __shared__ unsigned h_u32[2][16][36];   // packed f16 pairs [buf][batch][feat-pair]
    __shared__ float    zp_lds[16][68];
    __shared__ float    red_lds[4];
    __shared__ unsigned cnt;

    for (int i = tid; i < 2 * 16 * 36; i += 256) (&h_u32[0][0][0])[i] = 0u;
    if (tid == 0) cnt = 0u;

    // Weight fragments: lane (c,g4) holds W[gate*64 + 16w + c][kt*32 + 8g4 + i]
    f16x8 bih[3][2], bhh[3][2];
#pragma unroll
    for (int gate = 0; gate < 3; ++gate) {
#pragma unroll
        for (int kt = 0; kt < 2; ++kt) {
            const float* p1 = W_ih + (gate * 64 + w * 16 + c) * 64 + kt * 32 + g4 * 8;
            bih[gate][kt] = pack8(*(const f32x4*)p1, *(const f32x4*)(p1 + 4));
            const float* p2 = W_hh + (gate * 64 + w * 16 + c) * 64 + kt * 32 + g4 * 8;
            bhh[gate][kt] = pack8(*(const f32x4*)p2, *(const f32x4*)(p2 + 4));
        }
    }

    // Per-reg bias vectors: reg r <-> gate feature f = 16w + 4g4 + r
    f32x4 bRq, bZq, bNXq, bNHq;
#pragma unroll
    for (int r = 0; r < 4; ++r) {
        const int f = w * 16 + g4 * 4 + r;
        bRq[r]  = b_ih[f]       + b_hh[f];
        bZq[r]  = b_ih[64 + f]  + b_hh[64 + f];
        bNXq[r] = b_ih[128 + f];
        bNHq[r] = b_hh[128 + f];
    }

    const int sl_c = seql[b0 + c];
    const int tmax = seql[b0];       // sorted descending -> block max
    float hp[4] = {0.f, 0.f, 0.f, 0.f};

    const float* vrow = values + (size_t)(b0 + c) * T_ * NV_ + g4 * 8;
    const float* mrow = mask   + (size_t)(b0 + c) * T_ * NV_ + g4 * 8;

    // depth-6 prefetch, named sets A..F (static register indexing)
#define DECLSET(S) f32x4 S##v0, S##v1, S##m0, S##m1
    DECLSET(A); DECLSET(B); DECLSET(C); DECLSET(D); DECLSET(E); DECLSET(F);
#define FILLSET(S, tc) do {                                                  \
        const int tt_ = ((tc) < tmax) ? (tc) : 0;                            \
        const float* vp_ = vrow + (T_ - 1 - tt_) * NV_;                      \
        const float* mp_ = mrow + (T_ - 1 - tt_) * NV_;                      \
        S##v0 = *(const f32x4*)vp_; S##v1 = *(const f32x4*)(vp_ + 4);        \
        S##m0 = *(const f32x4*)mp_; S##m1 = *(const f32x4*)(mp_ + 4);        \
    } while (0)
    FILLSET(A, 0); FILLSET(B, 1); FILLSET(C, 2);
    FILLSET(D, 3); FILLSET(E, 4); FILLSET(F, 5);

    __syncthreads();   // h zero-init + cnt init visibility (one-time)

#define GSTEP(S, tc) do {                                                    \
        f16x8 ha0 = *(const f16x8*)&h_u32[(tc) & 1][c][4 * g4];              \
        f16x8 ha1 = *(const f16x8*)&h_u32[(tc) & 1][c][16 + 4 * g4];         \
        f16x8 xa0 = pack8(S##v0, S##v1);                                     \
        f16x8 xa1 = pack8(S##m0, S##m1);                                     \
        FILLSET(S, (tc) + DEPTH);                                            \
        f32x4 accR  = MFMA16(bih[0][0], xa0, bRq);                           \
        f32x4 accNX = MFMA16(bih[2][0], xa0, bNXq);                          \
        f32x4 accZ  = MFMA16(bih[1][0], xa0, bZq);                           \
        accR  = MFMA16(bih[0][1], xa1, accR);                                \
        accNX = MFMA16(bih[2][1], xa1, accNX);                               \
        accZ  = MFMA16(bih[1][1], xa1, accZ);                                \
        f32x4 accNH = MFMA16(bhh[2][0], ha0, bNHq);                          \
        accR  = MFMA16(bhh[0][0], ha0, accR);                                \
        accNH = MFMA16(bhh[2][1], ha1, accNH);                               \
        accR  = MFMA16(bhh[0][1], ha1, accR);                                \
        accZ  = MFMA16(bhh[1][0], ha0, accZ);                                \
        accZ  = MFMA16(bhh[1][1], ha1, accZ);                                \
        const bool act = ((tc) < sl_c);                                      \
        _Pragma("unroll")                                                    \
        for (int r = 0; r < 4; ++r) {                                        \
            float rr   = sigm(accR[r]);                                      \
            float zz   = sigm(accZ[r]);                                      \
            float nn   = tanh_(accNX[r] + rr * accNH[r]);                    \
            float hnew = nn + zz * (hp[r] - nn);                             \
            if (act) hp[r] = hnew;                                           \
        }                                                                    \
        f16x4 hq;                                                            \
        _Pragma("unroll")                                                    \
        for (int r = 0; r < 4; ++r) hq[r] = (_Float16)hp[r];                 \
        *(f16x4*)&h_u32[((tc) & 1) ^ 1][c][8 * w + 2 * g4] = hq;             \
        asm volatile("s_waitcnt lgkmcnt(0)" ::: "memory");                   \
        if (l == 0) atomicAdd(&cnt, 1u);                                     \
        asm volatile("" ::: "memory");                                       \
        {                                                                    \
            const unsigned tgt_ = 4u * ((unsigned)(tc) + 1u);                \
            while (__builtin_amdgcn_readfirstlane(                           \
                       *(volatile unsigned*)&cnt) < tgt_) { }                \
        }                                                                    \
        asm volatile("" ::: "memory");                                       \
    } while (0)

    int t = 0;
    while (true) {
        GSTEP(A, t); if (++t >= tmax) break;
        GSTEP(B, t); if (++t >= tmax) break;
        GSTEP(C, t); if (++t >= tmax) break;
        GSTEP(D, t); if (++t >= tmax) break;
        GSTEP(E, t); if (++t >= tmax) break;
        GSTEP(F, t); if (++t >= tmax) break;
    }

    // z0p^T = W_z0 * h^T + b_z0 : rows 16w+4g4+r, batch c
    f16x8 az0f[2];
#pragma unroll
    for (int kt = 0; kt < 2; ++kt) {
        const float* p = W_z0 + (w * 16 + c) * 64 + kt * 32 + g4 * 8;
        az0f[kt] = pack8(*(const f32x4*)p, *(const f32x4*)(p + 4));
    }
    const int fin = tmax & 1;
    f16x8 hf0 = *(const f16x8*)&h_u32[fin][c][4 * g4];
    f16x8 hf1 = *(const f16x8*)&h_u32[fin][c][16 + 4 * g4];
    f32x4 az;
#pragma unroll
    for (int r = 0; r < 4; ++r) az[r] = b_z0[w * 16 + g4 * 4 + r];
    az = MFMA16(az0f[0], hf0, az);
    az = MFMA16(az0f[1], hf1, az);
    *(f32x4*)&zp_lds[c][w * 16 + g4 * 4] = az;
    __syncthreads();

    // z0 = mean + eps*exp(0.5*logvar); KL partial sum
    const int row = tid >> 4;
    const int j2  = (tid & 15) * 2;
    float m0 = zp_lds[row][j2],      m1 = zp_lds[row][j2 + 1];
    float v0 = zp_lds[row][32 + j2], v1 = zp_lds[row][32 + j2 + 1];
    const float* erow = eps + (size_t)(b0 + row) * L_;
    float e0 = erow[j2], e1 = erow[j2 + 1];
    float* zrow = z0ws + (size_t)(b0 + row) * L_;
    float s0 = __expf(0.5f * v0), s1 = __expf(0.5f * v1);
    zrow[j2]     = m0 + e0 * s0;
    zrow[j2 + 1] = m1 + e1 * s1;
    float kls = (1.0f + v0 - m0 * m0 - s0 * s0) + (1.0f + v1 - m1 * m1 - s1 * s1);
#pragma unroll
    for (int off = 32; off >= 1; off >>= 1) kls += __shfl_down(kls, off);
    if (l == 0) red_lds[w] = kls;
    __syncthreads();
    if (tid == 0) parts[blockIdx.x] = red_lds[0] + red_lds[1] + red_lds[2] + red_lds[3];
}

// ---------------------------------------------------------------------------
// ODE (RK4, NSTEP fixed steps over [0,48]) + decoder. One wave / 16 rows.
// ---------------------------------------------------------------------------
__global__ __launch_bounds__(64) void ode_kernel(
    const float* __restrict__ z0ws,
    const float* __restrict__ oW1, const float* __restrict__ ob1,
    const float* __restrict__ oW2, const float* __restrict__ ob2,
    const float* __restrict__ oW3, const float* __restrict__ ob3,
    const float* __restrict__ dW1, const float* __restrict__ db1,
    const float* __restrict__ dW2, const float* __restrict__ db2,
    float* __restrict__ out)
{
    const int l  = threadIdx.x;
    const int c  = l & 15;
    const int g4 = l >> 4;
    const int b0 = blockIdx.x * 16;

    __shared__ _Float16 zbuf[16][40];
    __shared__ _Float16 buf1[16][72];
    __shared__ _Float16 buf2[16][72];

    f16x8 w1f[4], d1f[4], w2f[4][2], w3f[2][2];
#pragma unroll
    for (int mt = 0; mt < 4; ++mt) {
        const float* p = oW1 + (mt * 16 + c) * 32 + g4 * 8;
        w1f[mt] = pack8(*(const f32x4*)p, *(const f32x4*)(p + 4));
        const float* q = dW1 + (mt * 16 + c) * 32 + g4 * 8;
        d1f[mt] = pack8(*(const f32x4*)q, *(const f32x4*)(q + 4));
#pragma unroll
        for (int kt = 0; kt < 2; ++kt) {
            const float* r = oW2 + (mt * 16 + c) * 64 + kt * 32 + g4 * 8;
            w2f[mt][kt] = pack8(*(const f32x4*)r, *(const f32x4*)(r + 4));
        }
    }
#pragma unroll
    for (int mt = 0; mt < 2; ++mt) {
#pragma unroll
        for (int kt = 0; kt < 2; ++kt) {
            const float* r = oW3 + (mt * 16 + c) * 64 + kt * 32 + g4 * 8;
            w3f[mt][kt] = pack8(*(const f32x4*)r, *(const f32x4*)(r + 4));
        }
    }

    f32x4 b1q[4], b2q[4], d1q[4], w2q[4], b3q[2];
#pragma unroll
    for (int mt = 0; mt < 4; ++mt) {
#pragma unroll
        for (int r = 0; r < 4; ++r) {
            b1q[mt][r] = ob1[mt * 16 + g4 * 4 + r];
            b2q[mt][r] = ob2[mt * 16 + g4 * 4 + r];
            d1q[mt][r] = db1[mt * 16 + g4 * 4 + r];
            w2q[mt][r] = dW2[mt * 16 + g4 * 4 + r];
        }
    }
#pragma unroll
    for (int mt = 0; mt < 2; ++mt) {
#pragma unroll
        for (int r = 0; r < 4; ++r) b3q[mt][r] = ob3[mt * 16 + g4 * 4 + r];
    }
    const float bd2 = db2[0];

    f32x4 z[2];
#pragma unroll
    for (int mt = 0; mt < 2; ++mt)
        z[mt] = *(const f32x4*)(z0ws + (size_t)(b0 + c) * L_ + mt * 16 + g4 * 4);

    auto evalf = [&](const f32x4* zin, f32x4* kout) {
#pragma unroll
        for (int mt = 0; mt < 2; ++mt) {
            f16x4 hv;
#pragma unroll
            for (int r = 0; r < 4; ++r) hv[r] = (_Float16)zin[mt][r];
            *(f16x4*)&zbuf[c][mt * 16 + g4 * 4] = hv;
        }
        f16x8 zf = *(const f16x8*)&zbuf[c][g4 * 8];

        f32x4 h1[4];
#pragma unroll
        for (int mt = 0; mt < 4; ++mt) h1[mt] = MFMA16(w1f[mt], zf, b1q[mt]);
#pragma unroll
        for (int mt = 0; mt < 4; ++mt) {
            f16x4 hv;
#pragma unroll
            for (int r = 0; r < 4; ++r) hv[r] = (_Float16)tanh_(h1[mt][r]);
            *(f16x4*)&buf1[c][mt * 16 + g4 * 4] = hv;
        }
        f16x8 a1 = *(const f16x8*)&buf1[c][g4 * 8];
        f16x8 a2 = *(const f16x8*)&buf1[c][32 + g4 * 8];

        f32x4 h2[4];
#pragma unroll
        for (int mt = 0; mt < 4; ++mt) {
            h2[mt] = MFMA16(w2f[mt][0], a1, b2q[mt]);
            h2[mt] = MFMA16(w2f[mt][1], a2, h2[mt]);
        }
#pragma unroll
        for (int mt = 0; mt < 4; ++mt) {
            f16x4 hv;
#pragma unroll
            for (int r = 0; r < 4; ++r) hv[r] = (_Float16)tanh_(h2[mt][r]);
            *(f16x4*)&buf2[c][mt * 16 + g4 * 4] = hv;
        }
        f16x8 a3 = *(const f16x8*)&buf2[c][g4 * 8];
        f16x8 a4 = *(const f16x8*)&buf2[c][32 + g4 * 8];

#pragma unroll
        for (int mt = 0; mt < 2; ++mt) {
            kout[mt] = MFMA16(w3f[mt][0], a3, b3q[mt]);
            kout[mt] = MFMA16(w3f[mt][1], a4, kout[mt]);
        }
    };

    const float dt = 48.0f / (float)NSTEP;
    for (int s = 0; s < NSTEP; ++s) {
        f32x4 k[2], ks[2], zt[2];
        evalf(z, k);
#pragma unroll
        for (int mt = 0; mt < 2; ++mt) { ks[mt] = k[mt]; zt[mt] = z[mt] + k[mt] * (0.5f * dt); }
        evalf(zt, k);
#pragma unroll
        for (int mt = 0; mt < 2; ++mt) { ks[mt] += k[mt] * 2.0f; zt[mt] = z[mt] + k[mt] * (0.5f * dt); }
        evalf(zt, k);
#pragma unroll
        for (int mt = 0; mt < 2; ++mt) { ks[mt] += k[mt] * 2.0f; zt[mt] = z[mt] + k[mt] * dt; }
        evalf(zt, k);
#pragma unroll
        for (int mt = 0; mt < 2; ++mt) z[mt] += (ks[mt] + k[mt]) * (dt / 6.0f);
    }

#pragma unroll
    for (int mt = 0; mt < 2; ++mt) {
        f16x4 hv;
#pragma unroll
        for (int r = 0; r < 4; ++r) hv[r] = (_Float16)z[mt][r];
        *(f16x4*)&zbuf[c][mt * 16 + g4 * 4] = hv;
    }
    f16x8 zf = *(const f16x8*)&zbuf[c][g4 * 8];
    float p = 0.0f;
#pragma unroll
    for (int mt = 0; mt < 4; ++mt) {
        f32x4 d = MFMA16(d1f[mt], zf, d1q[mt]);
#pragma unroll
        for (int r = 0; r < 4; ++r) p += fmaxf(d[r], 0.0f) * w2q[mt][r];
    }
    p += __shfl_xor(p, 16);
    p += __shfl_xor(p, 32);
    if (l < 16) out[b0 + c] = p + bd2;
}

__global__ __launch_bounds__(128) void kl_fin(const float* __restrict__ parts,
                                              float* __restrict__ out)
{
    __shared__ float sred[2];
    const int tid = threadIdx.x;
    float p = parts[tid];
#pragma unroll
    for (int off = 32; off >= 1; off >>= 1) p += __shfl_down(p, off);
    if ((tid & 63) == 0) sred[tid >> 6] = p;
    __syncthreads();
    if (tid == 0) out[B_] = -0.5f * (sred[0] + sred[1]) / (float)(B_ * L_);
}

extern "C" void kernel_launch(void* const* d_in, const int* in_sizes, int n_in,
                              void* d_out, int out_size, void* d_ws, size_t ws_size,
                              hipStream_t stream) {
    const float* values = (const float*)d_in[1];
    const float* mask   = (const float*)d_in[2];
    const int*   seql   = (const int*)d_in[3];
    const float* eps    = (const float*)d_in[4];
    const float* W_ih   = (const float*)d_in[5];
    const float* W_hh   = (const float*)d_in[6];
    const float* b_ih   = (const float*)d_in[7];
    const float* b_hh   = (const float*)d_in[8];
    const float* W_z0   = (const float*)d_in[9];
    const float* b_z0   = (const float*)d_in[10];
    const float* oW1    = (const float*)d_in[11];
    const float* ob1    = (const float*)d_in[12];
    const float* oW2    = (const float*)d_in[13];
    const float* ob2    = (const float*)d_in[14];
    const float* oW3    = (const float*)d_in[15];
    const float* ob3    = (const float*)d_in[16];
    const float* dW1    = (const float*)d_in[17];
    const float* db1    = (const float*)d_in[18];
    const float* dW2    = (const float*)d_in[19];
    const float* db2    = (const float*)d_in[20];
    float* out = (float*)d_out;

    float* z0ws  = (float*)d_ws;
    float* parts = z0ws + (size_t)B_ * L_;

    hipLaunchKernelGGL(gru_kernel, dim3(B_ / 16), dim3(256), 0, stream,
                       values, mask, seql, eps, W_ih, W_hh, b_ih, b_hh, W_z0, b_z0,
                       z0ws, parts);
    hipLaunchKernelGGL(ode_kernel, dim3(B_ / 16), dim3(64), 0, stream,
                       z0ws, oW1, ob1, oW2, ob2, oW3, ob3, dW1, db1, dW2, db2, out);
    hipLaunchKernelGGL(kl_fin, dim3(1), dim3(128), 0, stream, parts, out);
}